// Round 1
// baseline (32.581 us; speedup 1.0000x reference)
//
#include <hip/hip_runtime.h>

#define MAXF 4096

// ---------------------------------------------------------------------------
// Kernel 1: per-batch cumsum(ds) -> idx table (scatter form of searchsorted),
// plus pitch gather and total write. One block (512 threads) per batch row.
// ---------------------------------------------------------------------------
__global__ __launch_bounds__(512) void lr_prep(
    const float* __restrict__ notepitch,  // (B, T)
    const int* __restrict__ ds,           // (B, T)
    int* __restrict__ idx_ws,             // (B, MAXF)  -1 => masked/pad
    float* __restrict__ pitch_out,        // (B, MAXF)
    float* __restrict__ total_out,        // (B,) stored as float
    int T)
{
    const int b = blockIdx.x;
    const int t = threadIdx.x;

    __shared__ int cum[512];
    __shared__ int idx_sh[MAXF];

    int v = (t < T) ? ds[b * T + t] : 0;
    cum[t] = v;
    __syncthreads();

    // Hillis-Steele inclusive scan over 512 entries
    for (int off = 1; off < 512; off <<= 1) {
        int x = cum[t];
        int y = (t >= off) ? cum[t - off] : 0;
        __syncthreads();
        cum[t] = x + y;
        __syncthreads();
    }

    int total = cum[T - 1];
    if (total == 0) {
        // row_zero: ds -> all ones => cum[t] = t+1
        cum[t] = t + 1;
        total = T;
    }
    __syncthreads();

    // init idx to sentinel
    for (int p = t; p < MAXF; p += 512) idx_sh[p] = -1;
    __syncthreads();

    // scatter: positions [cum[t-1], cum[t]) map to source index t
    // (== searchsorted(cum, pos, side='right') for pos < total)
    if (t < T) {
        int lo = (t > 0) ? cum[t - 1] : 0;
        int hi = cum[t];
        for (int p = lo; p < hi; ++p) idx_sh[p] = t;
    }
    __syncthreads();

    // write idx table, pitch output
    for (int p = t; p < MAXF; p += 512) {
        int id = idx_sh[p];
        idx_ws[b * MAXF + p] = id;
        pitch_out[(size_t)b * MAXF + p] = (id >= 0) ? notepitch[b * T + id] : 0.0f;
    }
    if (t == 0) total_out[b] = (float)total;
}

// ---------------------------------------------------------------------------
// Kernel 2: out[b,c,pos] = idx[b,pos] >= 0 ? xs[b,c,idx] : 0
// One block per (b,c) row. int4 idx loads, float4 coalesced stores.
// ---------------------------------------------------------------------------
__global__ __launch_bounds__(256) void lr_gather(
    const float* __restrict__ xs,       // (B, C, T)
    const int* __restrict__ idx_ws,     // (B, MAXF)
    float* __restrict__ out,            // (B, C, MAXF)
    int T, int C)
{
    const int row = blockIdx.x;          // b*C + c
    const int b = row / C;
    const float* __restrict__ xrow = xs + (size_t)row * T;
    const int* __restrict__ irow  = idx_ws + b * MAXF;
    float* __restrict__ orow      = out + (size_t)row * MAXF;

    const int t = threadIdx.x;
#pragma unroll
    for (int i = 0; i < MAXF / (256 * 4); ++i) {
        int p4 = (i * 256 + t) * 4;
        int4 id = *reinterpret_cast<const int4*>(irow + p4);
        float4 v;
        v.x = (id.x >= 0) ? xrow[id.x] : 0.0f;
        v.y = (id.y >= 0) ? xrow[id.y] : 0.0f;
        v.z = (id.z >= 0) ? xrow[id.z] : 0.0f;
        v.w = (id.w >= 0) ? xrow[id.w] : 0.0f;
        *reinterpret_cast<float4*>(orow + p4) = v;
    }
}

extern "C" void kernel_launch(void* const* d_in, const int* in_sizes, int n_in,
                              void* d_out, int out_size, void* d_ws, size_t ws_size,
                              hipStream_t stream) {
    const float* xs        = (const float*)d_in[0];
    const float* notepitch = (const float*)d_in[1];
    const int*   ds        = (const int*)d_in[2];
    // d_in[3] = x_lengths: unused by the reference computation

    const int B = in_sizes[3];
    const int T = in_sizes[1] / B;
    const int C = in_sizes[0] / (B * T);

    float* out       = (float*)d_out;
    float* pitch_out = out + (size_t)B * C * MAXF;
    float* total_out = pitch_out + (size_t)B * MAXF;

    int* idx_ws = (int*)d_ws;  // B*MAXF ints = 256 KB

    lr_prep<<<B, 512, 0, stream>>>(notepitch, ds, idx_ws, pitch_out, total_out, T);
    lr_gather<<<B * C, 256, 0, stream>>>(xs, idx_ws, out, T, C);
}

// Round 2
// 28.754 us; speedup vs baseline: 1.1331x; 1.1331x over previous
//
#include <hip/hip_runtime.h>

#define MAXF 4096
#define CG 8          // channels per block

// ---------------------------------------------------------------------------
// Fused: per block = (batch b, channel-group of CG).
//  1. scan ds[b,:] in LDS (Hillis-Steele over 512)  -- redundant per b, but
//     amortized CG x and overlapped across blocks
//  2. scatter-build idx table in LDS (== searchsorted(cum, pos, 'right'))
//  3. gather CG channels with float4 stores; idx quad reused in registers
//  4. cg==0 block also writes pitch + total
// ---------------------------------------------------------------------------
__global__ __launch_bounds__(512) void lr_fused(
    const float* __restrict__ xs,         // (B, C, T)
    const float* __restrict__ notepitch,  // (B, T)
    const int* __restrict__ ds,           // (B, T)
    float* __restrict__ out,              // (B, C, MAXF)
    float* __restrict__ pitch_out,        // (B, MAXF)
    float* __restrict__ total_out,        // (B,) as float
    int T, int C)
{
    const int b  = blockIdx.y;
    const int cg = blockIdx.x;
    const int t  = threadIdx.x;

    __shared__ int cum[512];
    __shared__ int idx_sh[MAXF];

    int v = (t < T) ? ds[b * T + t] : 0;
    cum[t] = v;
    __syncthreads();

    // inclusive scan over 512 entries
    for (int off = 1; off < 512; off <<= 1) {
        int x = cum[t];
        int y = (t >= off) ? cum[t - off] : 0;
        __syncthreads();
        cum[t] = x + y;
        __syncthreads();
    }

    int total = cum[T - 1];
    if (total == 0) {          // row_zero: ds -> all ones => cum[t] = t+1
        cum[t] = t + 1;
        total = T;
    }
    __syncthreads();

    for (int p = t; p < MAXF; p += 512) idx_sh[p] = -1;
    __syncthreads();

    if (t < T) {
        int lo = (t > 0) ? cum[t - 1] : 0;
        int hi = cum[t];
        if (hi > MAXF) hi = MAXF;
        for (int p = lo; p < hi; ++p) idx_sh[p] = t;
    }
    __syncthreads();

    const float* __restrict__ xbase = xs  + ((size_t)b * C + (size_t)cg * CG) * T;
    float* __restrict__       obase = out + ((size_t)b * C + (size_t)cg * CG) * MAXF;

#pragma unroll
    for (int i = 0; i < MAXF / (512 * 4); ++i) {   // 2 iterations
        const int p4 = (i * 512 + t) * 4;
        int4 id = *reinterpret_cast<const int4*>(&idx_sh[p4]);
#pragma unroll
        for (int ch = 0; ch < CG; ++ch) {
            const float* __restrict__ xrow = xbase + (size_t)ch * T;
            float4 vv;
            vv.x = (id.x >= 0) ? xrow[id.x] : 0.0f;
            vv.y = (id.y >= 0) ? xrow[id.y] : 0.0f;
            vv.z = (id.z >= 0) ? xrow[id.z] : 0.0f;
            vv.w = (id.w >= 0) ? xrow[id.w] : 0.0f;
            *reinterpret_cast<float4*>(obase + (size_t)ch * MAXF + p4) = vv;
        }
    }

    if (cg == 0) {
        for (int p = t; p < MAXF; p += 512) {
            int id = idx_sh[p];
            pitch_out[(size_t)b * MAXF + p] = (id >= 0) ? notepitch[b * T + id] : 0.0f;
        }
        if (t == 0) total_out[b] = (float)total;
    }
}

extern "C" void kernel_launch(void* const* d_in, const int* in_sizes, int n_in,
                              void* d_out, int out_size, void* d_ws, size_t ws_size,
                              hipStream_t stream) {
    const float* xs        = (const float*)d_in[0];
    const float* notepitch = (const float*)d_in[1];
    const int*   ds        = (const int*)d_in[2];
    // d_in[3] = x_lengths: unused by the reference computation

    const int B = in_sizes[3];
    const int T = in_sizes[1] / B;
    const int C = in_sizes[0] / (B * T);

    float* out       = (float*)d_out;
    float* pitch_out = out + (size_t)B * C * MAXF;
    float* total_out = pitch_out + (size_t)B * MAXF;

    dim3 grid(C / CG, B);
    lr_fused<<<grid, 512, 0, stream>>>(xs, notepitch, ds, out, pitch_out, total_out, T, C);
}